// Round 14
// baseline (255.387 us; speedup 1.0000x reference)
//
#include <hip/hip_runtime.h>
#include <hip/hip_bf16.h>
#include <stdint.h>

#define BATCH 4
#define SEQ   4096
#define DIM   2048
#define NFREQ 1025
#define NCPLX 1024
#define ROWS  (BATCH*SEQ)   // 16384

// fused chunk decomposition
#define SCH  16            // rows per block (sequential, cumsum in regs)
#define NSC  (SEQ/SCH)     // 256 chunks per batch
#define NSCG 16            // chunks per scan group
#define NGRP (NSC/NSCG)    // 16 groups

#define SPEC_STRIDE 257    // uint4 per row: 256 pair-packed + 1 extra (k=512)

typedef __bf16 bf16x8 __attribute__((ext_vector_type(8)));
typedef float  f32x4  __attribute__((ext_vector_type(4)));

__device__ __forceinline__ int drev4(int n) {  // reverse 5 base-4 digits of 10-bit n
  return ((n&3)<<8) | (((n>>2)&3)<<6) | (((n>>4)&3)<<4) | (((n>>6)&3)<<2) | ((n>>8)&3);
}
#define ZI(i) ((i) + ((i)>>4))   // LDS pad: every 16 float2 -> +1 (caps conflicts ~4-way)

__device__ __forceinline__ float2 cmulf(float2 a, float2 b) {
  return make_float2(a.x*b.x - a.y*b.y, a.x*b.y + a.y*b.x);
}

__device__ __forceinline__ unsigned short f2bf(float f) {
  union { float f; unsigned u; } v; v.f = f;
  unsigned r = v.u + 0x7fffu + ((v.u >> 16) & 1u);
  return (unsigned short)(r >> 16);
}
__device__ __forceinline__ unsigned packbf(float2 v) {
  return (unsigned)f2bf(v.x) | ((unsigned)f2bf(v.y) << 16);
}
__device__ __forceinline__ float2 unpackbf(unsigned u) {
  union { unsigned u; float f; } a, b;
  a.u = u << 16; b.u = u & 0xffff0000u;
  return make_float2(a.f, b.f);
}

// ---------------- radix-4 butterflies (dual-row batched) ----------------------
template<int INV>
__device__ __forceinline__ void bfly4(float2* z, int i0, int q,
                                      float2 w1, float2 w2, float2 w3) {
  float2 x0 = z[ZI(i0)];
  float2 x1 = cmulf(z[ZI(i0+q)],   w1);
  float2 x2 = cmulf(z[ZI(i0+2*q)], w2);
  float2 x3 = cmulf(z[ZI(i0+3*q)], w3);
  float2 a = make_float2(x0.x+x2.x, x0.y+x2.y), b = make_float2(x0.x-x2.x, x0.y-x2.y);
  float2 c = make_float2(x1.x+x3.x, x1.y+x3.y), d = make_float2(x1.x-x3.x, x1.y-x3.y);
  z[ZI(i0)]     = make_float2(a.x+c.x, a.y+c.y);
  z[ZI(i0+2*q)] = make_float2(a.x-c.x, a.y-c.y);
  if (!INV) { z[ZI(i0+q)]   = make_float2(b.x+d.y, b.y-d.x);
              z[ZI(i0+3*q)] = make_float2(b.x-d.y, b.y+d.x); }
  else      { z[ZI(i0+q)]   = make_float2(b.x-d.y, b.y+d.x);
              z[ZI(i0+3*q)] = make_float2(b.x+d.y, b.y-d.x); }
}
template<int INV>
__device__ __forceinline__ void bfly4_nw(float2* z, int i0) {  // q=1, no twiddle
  float2 x0=z[ZI(i0)], x1=z[ZI(i0+1)], x2=z[ZI(i0+2)], x3=z[ZI(i0+3)];
  float2 a = make_float2(x0.x+x2.x, x0.y+x2.y), b = make_float2(x0.x-x2.x, x0.y-x2.y);
  float2 c = make_float2(x1.x+x3.x, x1.y+x3.y), d = make_float2(x1.x-x3.x, x1.y-x3.y);
  z[ZI(i0)]   = make_float2(a.x+c.x, a.y+c.y);
  z[ZI(i0+2)] = make_float2(a.x-c.x, a.y-c.y);
  if (!INV) { z[ZI(i0+1)] = make_float2(b.x+d.y, b.y-d.x);
              z[ZI(i0+3)] = make_float2(b.x-d.y, b.y+d.x); }
  else      { z[ZI(i0+1)] = make_float2(b.x-d.y, b.y+d.x);
              z[ZI(i0+3)] = make_float2(b.x+d.y, b.y-d.x); }
}

// dual-row 1024-pt radix-4 DIT: same barrier count serves TWO rows
template<int INV>
__device__ __forceinline__ void fft_stages_tw2(float2* z0, float2* z1, int tid,
                                               const float2* tw1) {
  { int b4 = tid*4;
    bfly4_nw<INV>(z0, b4);
    bfly4_nw<INV>(z1, b4);
  }
  __syncthreads();
#pragma unroll
  for (int s = 0; s < 4; ++s) {
    const int lq = 2 + 2*s;          // q = 4,16,64,256
    const int q  = 1 << lq;
    int j = tid & (q-1), g = tid >> lq;
    int base = (g << (lq+2)) + j;
    float2 w1 = tw1[s]; if (INV) w1.y = -w1.y;
    float2 w2 = cmulf(w1, w1), w3 = cmulf(w2, w1);
    bfly4<INV>(z0, base, q, w1, w2, w3);
    bfly4<INV>(z1, base, q, w1, w2, w3);
    __syncthreads();
  }
}

__device__ __forceinline__ void make_tw1(int tid, float2* tw1) {
#pragma unroll
  for (int s = 0; s < 4; ++s) {
    const int lq = 2 + 2*s;
    const int q  = 1 << lq;
    int j = tid & (q-1);
    float ang = -6.2831853071795864769f * (float)j / (float)(4*q);
    float sw, cw; __sincosf(ang, &sw, &cw);
    tw1[s] = make_float2(cw, sw);
  }
}

// unpack packed-real spectrum values for k=tid (A) and k=tid+256 (B)
__device__ __forceinline__ void unpack_row(const float2* z, int tid,
    float cwA, float swA, float cwB, float swB,
    float2& vA, float2& vAp, float2& vB, float2& vBp) {
  float2 ZkA = z[ZI(tid)],     ZnA = z[ZI((NCPLX - tid) & (NCPLX-1))];
  float2 ZkB = z[ZI(tid+256)], ZnB = z[ZI(768 - tid)];
  float Er = 0.5f*(ZkA.x + ZnA.x), Ei = 0.5f*(ZkA.y - ZnA.y);
  float dr = 0.5f*(ZkA.x - ZnA.x), di = 0.5f*(ZkA.y + ZnA.y);
  vA  = make_float2( Er + cwA*di + swA*dr,  Ei + swA*di - cwA*dr);
  vAp = make_float2( Er - cwA*di - swA*dr, -Ei + swA*di - cwA*dr);
  float Fr = 0.5f*(ZkB.x + ZnB.x), Fi = 0.5f*(ZkB.y - ZnB.y);
  float er = 0.5f*(ZkB.x - ZnB.x), ei = 0.5f*(ZkB.y + ZnB.y);
  vB  = make_float2( Fr + cwB*ei + swB*er,  Fi + swB*ei - cwB*er);
  vBp = make_float2( Fr - cwB*ei - swB*er, -Fi + swB*ei - cwB*er);
}

// ============ merged fwd_fused + wfft, 2 rows per FFT pass ====================
__global__ __launch_bounds__(256) void fwd_wfft(const float* __restrict__ x,
                                                const float* __restrict__ w,
                                                const float* __restrict__ kvs,
                                                uint4* __restrict__ spec,
                                                float2* __restrict__ partial,
                                                unsigned short* __restrict__ H) {
  __shared__ float2 z0[ZI(1023)+2], z1[ZI(1023)+2];
  __shared__ __align__(16) unsigned short hrow[2][2048];
  const int tid = threadIdx.x;

  float2 tw1[4];
  make_tw1(tid, tw1);
  const int kA = tid, kB = tid + 256;
  float swA, cwA, swB, cwB;   // e^{-i pi k/1024}
  __sincosf(-3.14159265358979323846f * (float)kA / 1024.0f, &swA, &cwA);
  __sincosf(-3.14159265358979323846f * (float)kB / 1024.0f, &swB, &cwB);
  int id0 = ZI(drev4(2*tid)),     id1 = ZI(drev4(2*tid+1));
  int id2 = ZI(drev4(2*tid+512)), id3 = ZI(drev4(2*tid+513));

  if (blockIdx.x >= BATCH*NSC) {
    // ---- wfft path: 2 W rows per block ----
    const int e0 = (blockIdx.x - BATCH*NSC) * 2;
    const float* wr0 = w + (size_t)e0 * DIM;
    const float* wr1 = wr0 + DIM;
    float4 a0 = ((const float4*)wr0)[tid], a1 = ((const float4*)wr0)[tid + 256];
    float4 b0 = ((const float4*)wr1)[tid], b1 = ((const float4*)wr1)[tid + 256];
    z0[id0] = make_float2(a0.x, a0.y); z0[id1] = make_float2(a0.z, a0.w);
    z0[id2] = make_float2(a1.x, a1.y); z0[id3] = make_float2(a1.z, a1.w);
    z1[id0] = make_float2(b0.x, b0.y); z1[id1] = make_float2(b0.z, b0.w);
    z1[id2] = make_float2(b1.x, b1.y); z1[id3] = make_float2(b1.z, b1.w);
    __syncthreads();
    fft_stages_tw2<0>(z0, z1, tid, tw1);
    const float invN = 1.0f/2048.0f, twoN = 2.0f/2048.0f;
    float aA = (tid == 0) ? invN : twoN;
#pragma unroll
    for (int r = 0; r < 2; ++r) {
      const float2* z = r ? z1 : z0;
      float2 vA, vAp, vB, vBp;
      unpack_row(z, tid, cwA, swA, cwB, swB, vA, vAp, vB, vBp);
      unsigned short* hr = hrow[r];
      hr[tid]        = f2bf(aA   * vA.x);
      hr[1024 - tid] = f2bf(aA   * vAp.x);
      hr[256 + tid]  = f2bf(twoN * vB.x);
      hr[768 - tid]  = f2bf(twoN * vBp.x);
      if (tid) {
        hr[1024 + tid] = f2bf(twoN * vA.y);
        hr[2048 - tid] = f2bf(twoN * vAp.y);
      }
      hr[1280 + tid] = f2bf(twoN * vB.y);
      hr[1792 - tid] = f2bf(twoN * vBp.y);
      if (tid == 0) {
        float2 Z5 = z[ZI(512)];
        hr[512]  = f2bf(twoN * Z5.x);
        hr[1536] = f2bf(twoN * (-Z5.y));
      }
    }
    __syncthreads();
    ((uint4*)(H + (size_t)e0 * DIM))[tid]       = ((const uint4*)hrow[0])[tid];
    ((uint4*)(H + (size_t)(e0 + 1) * DIM))[tid] = ((const uint4*)hrow[1])[tid];
    return;
  }

  // ---- fwd path: 16 rows, 2 per FFT pass ----
  const int sc = blockIdx.x & (NSC-1), b = blockIdx.x >> 8;
  float2 sA={0,0}, sAp={0,0}, sB={0,0}, sBp={0,0}, s5={0,0};
  const size_t row0 = (size_t)b*SEQ + (size_t)sc*SCH;
  const float* xrow = x + row0*DIM;
  const float kvA = kvs[kA], kvAp = kvs[NCPLX - kA], kvB = kvs[kB], kvBp = kvs[768 - tid];

  for (int s = 0; s < SCH; s += 2) {
    const float* xr0 = xrow + (size_t)s*DIM;
    const float* xr1 = xr0 + DIM;
    float4 a0 = ((const float4*)xr0)[tid], a1 = ((const float4*)xr0)[tid + 256];
    float4 b0 = ((const float4*)xr1)[tid], b1 = ((const float4*)xr1)[tid + 256];
    z0[id0] = make_float2(a0.x, a0.y); z0[id1] = make_float2(a0.z, a0.w);
    z0[id2] = make_float2(a1.x, a1.y); z0[id3] = make_float2(a1.z, a1.w);
    z1[id0] = make_float2(b0.x, b0.y); z1[id1] = make_float2(b0.z, b0.w);
    z1[id2] = make_float2(b1.x, b1.y); z1[id3] = make_float2(b1.z, b1.w);
    __syncthreads();
    fft_stages_tw2<0>(z0, z1, tid, tw1);
#pragma unroll
    for (int r = 0; r < 2; ++r) {
      const float2* z = r ? z1 : z0;
      float2 vA, vAp, vB, vBp;
      unpack_row(z, tid, cwA, swA, cwB, swB, vA, vAp, vB, vBp);
      sA.x += vA.x;  sA.y += vA.y;   sAp.x += vAp.x; sAp.y += vAp.y;
      sB.x += vB.x;  sB.y += vB.y;   sBp.x += vBp.x; sBp.y += vBp.y;
      uint4* sprow = spec + (row0 + s + r) * SPEC_STRIDE;
      sprow[tid] = make_uint4(packbf(vA), packbf(vAp), packbf(vB), packbf(vBp));
      if (tid == 0) {
        float2 Z5 = z[ZI(512)];
        float2 v5 = make_float2(Z5.x, -Z5.y);
        s5.x += v5.x; s5.y += v5.y;
        ((unsigned*)(sprow + 256))[0] = packbf(v5);
      }
    }
    __syncthreads();                                   // z free for next scatter
  }
  float2* pp = partial + ((size_t)(b*NSC + sc)) * NFREQ;
  pp[kA]          = make_float2(kvA*sA.x,  kvA*sA.y);
  pp[NCPLX - kA]  = make_float2(kvAp*sAp.x, kvAp*sAp.y);
  pp[kB]          = make_float2(kvB*sB.x,  kvB*sB.y);
  pp[768 - tid]   = make_float2(kvBp*sBp.x, kvBp*sBp.y);
  if (tid == 0) { float kv5 = kvs[512]; pp[512] = make_float2(kv5*s5.x, kv5*s5.y); }
}

// ============ scanA: exclusive scan within group; write RAW group totals ======
__global__ __launch_bounds__(256) void scanA(float2* __restrict__ partial,
                                             float2* __restrict__ gtot) {
  int kc = blockIdx.x % 5, g = (blockIdx.x / 5) % NGRP, b = blockIdx.x / (5*NGRP);
  int k = kc*256 + threadIdx.x;
  if (k >= NFREQ) return;
  float2* p = partial + ((size_t)(b*NSC + g*NSCG)) * NFREQ + k;
  float2 run = {0.f, 0.f};
#pragma unroll
  for (int i = 0; i < NSCG; ++i) {
    float2 t = p[(size_t)i*NFREQ];
    p[(size_t)i*NFREQ] = run;                          // exclusive within group
    run.x += t.x; run.y += t.y;
  }
  gtot[((size_t)(b*NGRP + g)) * NFREQ + k] = run;      // raw group total
}

// ============ inv_fused: inline group-prefix + cumsum-apply -> spectral G =====
__global__ __launch_bounds__(256) void inv_fused(const uint4* __restrict__ spec,
                                                 const float* __restrict__ kvs,
                                                 const float* __restrict__ qs_,
                                                 const float2* __restrict__ partial,
                                                 const float2* __restrict__ gtot,
                                                 unsigned short* __restrict__ G) {
  __shared__ __align__(16) unsigned short grow[2][2048];   // double-buffered
  const int tid = threadIdx.x;
  const int sc = blockIdx.x & (NSC-1), b = blockIdx.x >> 8;
  const int kA = tid, kB = tid + 256;

  float ksA = kvs[kA], ksAp = kvs[NCPLX - kA], ksB = kvs[kB], ksBp = kvs[768 - tid];
  float qsA = qs_[kA], qsAp = qs_[NCPLX - kA], qsB = qs_[kB], qsBp = qs_[768 - tid];

  const float2* pp = partial + ((size_t)(b*NSC + sc)) * NFREQ;
  float2 CA  = pp[kA], CAp = pp[NCPLX-kA], CB = pp[kB], CBp = pp[768-tid];
  float ks5 = kvs[512], qs5 = qs_[512];
  float2 C5 = pp[512];
  // inline exclusive prefix over RAW group totals (replaces scanB kernel)
  {
    const int g = sc >> 4;
    const float2* gb = gtot + (size_t)b*NGRP*NFREQ;
    for (int gg = 0; gg < g; ++gg) {
      const float2* gr = gb + (size_t)gg*NFREQ;
      float2 a0 = gr[kA], a1 = gr[NCPLX-kA], a2 = gr[kB], a3 = gr[768-tid];
      CA.x += a0.x; CA.y += a0.y;   CAp.x += a1.x; CAp.y += a1.y;
      CB.x += a2.x; CB.y += a2.y;   CBp.x += a3.x; CBp.y += a3.y;
      if (tid == 0) { float2 a5 = gr[512]; C5.x += a5.x; C5.y += a5.y; }
    }
  }

  const size_t row0 = (size_t)b*SEQ + (size_t)sc*SCH;
  const uint4* sprow = spec + row0 * SPEC_STRIDE;
  uint4 sp = sprow[tid];
  unsigned spN = ((const unsigned*)(sprow + 256))[0];

  for (int s = 0; s < SCH; ++s) {
    uint4 spn; unsigned spNn;
    if (s+1 < SCH) {
      const uint4* nr = sprow + (size_t)(s+1) * SPEC_STRIDE;
      spn = nr[tid]; spNn = ((const unsigned*)(nr + 256))[0];
    }
    unsigned short* gw = grow[s & 1];
    float2 vA = unpackbf(sp.x), vAp = unpackbf(sp.y);
    float2 vB = unpackbf(sp.z), vBp = unpackbf(sp.w);
    CA.x  += vA.x*ksA;   CA.y  += vA.y*ksA;
    CAp.x += vAp.x*ksAp; CAp.y += vAp.y*ksAp;
    CB.x  += vB.x*ksB;   CB.y  += vB.y*ksB;
    CBp.x += vBp.x*ksBp; CBp.y += vBp.y*ksBp;
    float2 qvA  = make_float2(qsA *(vA.x*CA.x  - vA.y*CA.y),  qsA *(vA.x*CA.y  + vA.y*CA.x));
    float2 qvAp = make_float2(qsAp*(vAp.x*CAp.x- vAp.y*CAp.y),qsAp*(vAp.x*CAp.y+ vAp.y*CAp.x));
    float2 qvB  = make_float2(qsB *(vB.x*CB.x  - vB.y*CB.y),  qsB *(vB.x*CB.y  + vB.y*CB.x));
    float2 qvBp = make_float2(qsBp*(vBp.x*CBp.x- vBp.y*CBp.y),qsBp*(vBp.x*CBp.y+ vBp.y*CBp.x));
    // scatter spectral row: real cols {t,1024-t,256+t,768-t}, imag cols 1024+k
    gw[tid]        = f2bf(qvA.x);
    gw[1024 - tid] = f2bf(qvAp.x);
    gw[256 + tid]  = f2bf(qvB.x);
    gw[768 - tid]  = f2bf(qvBp.x);
    if (tid) {
      gw[1024 + tid] = f2bf(qvA.y);
      gw[2048 - tid] = f2bf(qvAp.y);
    }
    gw[1280 + tid] = f2bf(qvB.y);
    gw[1792 - tid] = f2bf(qvBp.y);
    if (tid == 0) {
      float2 v5 = unpackbf(spN);
      C5.x += v5.x*ks5; C5.y += v5.y*ks5;
      gw[512]  = f2bf(qs5*(v5.x*C5.x - v5.y*C5.y));
      gw[1536] = f2bf(qs5*(v5.x*C5.y + v5.y*C5.x));
    }
    __syncthreads();
    ((uint4*)(G + (row0 + s) * DIM))[tid] = ((const uint4*)gw)[tid];
    // no trailing barrier: next iteration scatters into the other buffer
    sp = spn; spN = spNn;
  }
}

// ============ 256x256 8-phase GEMM: C[M,N] = A[M,K] * B[N,K]^T, bf16->fp32 =====
#define NKT (DIM/64)      // 32 K-tiles
#define NIT (NKT/2)       // 16 iterations of 2 K-tiles

#define BAR()  __builtin_amdgcn_s_barrier()
#define VMW(N) do{ asm volatile("s_waitcnt vmcnt(" #N ")" ::: "memory"); __builtin_amdgcn_sched_barrier(0); }while(0)

#define LOADA(B_, MH) do{ _Pragma("unroll") for (int m_=0;m_<4;++m_) _Pragma("unroll") for (int kk_=0;kk_<2;++kk_){ \
    int rA_ = wm*64 + m_*16 + l15; \
    aF[m_][kk_] = *(const bf16x8*)(smem + ((B_)*2+(MH))*16384 + rA_*128 + ((kk_*64 + lhi*16) ^ ((rA_&7)<<4))); } }while(0)

#define LOADB(DST, B_, NH) do{ _Pragma("unroll") for (int n_=0;n_<2;++n_) _Pragma("unroll") for (int kk_=0;kk_<2;++kk_){ \
    int rB_ = wn*32 + n_*16 + l15; \
    DST[n_][kk_] = *(const bf16x8*)(smem + 65536 + ((B_)*2+(NH))*16384 + rB_*128 + ((kk_*64 + lhi*16) ^ ((rB_&7)<<4))); } }while(0)

#define MM(MH, NH, BF) do{ __builtin_amdgcn_s_setprio(1); \
    _Pragma("unroll") for (int kk_=0;kk_<2;++kk_) _Pragma("unroll") for (int m_=0;m_<4;++m_) _Pragma("unroll") for (int n_=0;n_<2;++n_) \
      acc[MH][NH][m_][n_] = __builtin_amdgcn_mfma_f32_16x16x32_bf16(aF[m_][kk_], BF[n_][kk_], acc[MH][NH][m_][n_], 0, 0, 0); \
    __builtin_amdgcn_s_setprio(0); }while(0)

#define STAGEH(REG, B_, H_, GP, ROW0, KT) do{ _Pragma("unroll") for (int c_=0;c_<2;++c_){ \
    int ci_ = c_*512 + tid; int r_ = ci_>>3, sl_ = ci_&7; \
    const unsigned short* sp_ = (GP) + (size_t)((ROW0) + (H_)*128 + r_)*DIM + (KT) + ((sl_ ^ (r_&7))*8); \
    __builtin_amdgcn_global_load_lds((const __attribute__((address_space(1))) void*)sp_, \
      (__attribute__((address_space(3))) void*)(smem + (REG) + ((B_)*2+(H_))*16384 + ci_*16), 16, 0, 0); } }while(0)

__global__ __launch_bounds__(512, 2) void gemm256(const unsigned short* __restrict__ A,
                                                  const unsigned short* __restrict__ B,
                                                  float* __restrict__ C) {
  __shared__ __align__(16) char smem[131072];
  const int tid = threadIdx.x;
  const int lane = tid & 63;
  const int wid  = tid >> 6;
  const int wm = wid >> 2, wn = wid & 3;
  const int l15 = lane & 15, lhi = lane >> 4;

  // XCD-grouped swizzle: XCD j (= bid%8) owns bm in [8j, 8j+8) for all bn
  const int xj = blockIdx.x & 7, tt = blockIdx.x >> 3;
  const int bm = xj * 8 + (tt >> 3), bn = tt & 7;
  const int m0 = bm * 256, n0 = bn * 256;

  f32x4 acc[2][2][4][2] = {};
  bf16x8 aF[4][2], bF0[2][2], bF1[2][2];

  STAGEH(0,     0,0, A, m0, 0);  STAGEH(65536, 0,0, B, n0, 0);
  STAGEH(65536, 0,1, B, n0, 0);  STAGEH(0,     0,1, A, m0, 0);
  STAGEH(0,     1,0, A, m0, 64); STAGEH(65536, 1,0, B, n0, 64);
  STAGEH(65536, 1,1, B, n0, 64); STAGEH(0,     1,1, A, m0, 64);
  VMW(8);
  BAR();

#pragma unroll 1
  for (int j = 0; j < NIT-1; ++j) {
    const int kA = (2*j+2)*64, kB = (2*j+3)*64;
    LOADA(0,0); LOADB(bF0, 0,0);
    BAR(); MM(0,0,bF0); BAR();
    LOADB(bF1, 0,1);
    STAGEH(0, 0,0, A, m0, kA); STAGEH(65536, 0,0, B, n0, kA);
    BAR(); MM(0,1,bF1); BAR();
    LOADA(0,1);
    STAGEH(65536, 0,1, B, n0, kA);
    BAR(); MM(1,0,bF0); BAR();
    STAGEH(0, 0,1, A, m0, kA);
    VMW(8);
    BAR(); MM(1,1,bF1); BAR();
    LOADA(1,0); LOADB(bF0, 1,0);
    BAR(); MM(0,0,bF0); BAR();
    LOADB(bF1, 1,1);
    STAGEH(0, 1,0, A, m0, kB); STAGEH(65536, 1,0, B, n0, kB);
    BAR(); MM(0,1,bF1); BAR();
    LOADA(1,1);
    STAGEH(65536, 1,1, B, n0, kB);
    BAR(); MM(1,0,bF0); BAR();
    STAGEH(0, 1,1, A, m0, kB);
    VMW(8);
    BAR(); MM(1,1,bF1); BAR();
  }
  LOADA(0,0); LOADB(bF0, 0,0);
  BAR(); MM(0,0,bF0); BAR();
  LOADB(bF1, 0,1);
  BAR(); MM(0,1,bF1); BAR();
  LOADA(0,1);
  BAR(); MM(1,0,bF0); BAR();
  VMW(0);
  BAR(); MM(1,1,bF1); BAR();
  LOADA(1,0); LOADB(bF0, 1,0);
  BAR(); MM(0,0,bF0); BAR();
  LOADB(bF1, 1,1);
  BAR(); MM(0,1,bF1); BAR();
  LOADA(1,1);
  BAR(); MM(1,0,bF0); BAR();
  BAR(); MM(1,1,bF1); BAR();

  const int crow = lhi * 4;
#pragma unroll
  for (int mh = 0; mh < 2; ++mh)
#pragma unroll
    for (int nh = 0; nh < 2; ++nh)
#pragma unroll
      for (int m_ = 0; m_ < 4; ++m_)
#pragma unroll
        for (int n_ = 0; n_ < 2; ++n_) {
          float* cp = C + (size_t)(m0 + mh*128 + wm*64 + m_*16 + crow) * DIM
                        + (n0 + nh*128 + wn*32 + n_*16 + l15);
#pragma unroll
          for (int j2 = 0; j2 < 4; ++j2)
            cp[(size_t)j2 * DIM] = acc[mh][nh][m_][n_][j2];
        }
}

// ---------------- launch -------------------------------------------------------
extern "C" void kernel_launch(void* const* d_in, const int* in_sizes, int n_in,
                              void* d_out, int out_size, void* d_ws, size_t ws_size,
                              hipStream_t stream) {
  const float* x    = (const float*)d_in[0];
  const float* qry  = (const float*)d_in[1];
  const float* kvs  = (const float*)d_in[2];
  const float* wout = (const float*)d_in[3];
  float* out = (float*)d_out;

  char* ws = (char*)d_ws;
  size_t off = 0;
  uint4* spec = (uint4*)(ws + off);                     // 67.4 MB
  off += (size_t)ROWS * SPEC_STRIDE * sizeof(uint4);
  off = (off + 255) & ~(size_t)255;
  unsigned short* G = (unsigned short*)(ws + off);      // 67 MB (spectral A)
  off += (size_t)ROWS * DIM * sizeof(unsigned short);
  off = (off + 255) & ~(size_t)255;
  unsigned short* H = (unsigned short*)(ws + off);      // 8.4 MB (spectral W)
  off += (size_t)DIM * DIM * sizeof(unsigned short);
  off = (off + 255) & ~(size_t)255;
  float2* partial = (float2*)(ws + off);                // 8.4 MB
  off += (size_t)BATCH * NSC * NFREQ * sizeof(float2);
  off = (off + 255) & ~(size_t)255;
  float2* gtot = (float2*)(ws + off);                   // 0.5 MB (raw group totals)
  off += (size_t)BATCH * NGRP * NFREQ * sizeof(float2);

  hipLaunchKernelGGL(fwd_wfft,  dim3(BATCH*NSC + DIM/2), dim3(256), 0, stream, x, wout, kvs, spec, partial, H);
  hipLaunchKernelGGL(scanA,     dim3(BATCH*NGRP*5),      dim3(256), 0, stream, partial, gtot);
  hipLaunchKernelGGL(inv_fused, dim3(BATCH*NSC),         dim3(256), 0, stream, spec, kvs, qry, partial, gtot, G);
  hipLaunchKernelGGL(gemm256,   dim3((ROWS/256)*(DIM/256)), dim3(512), 0, stream, G, H, out);
}

// Round 15
// 218.246 us; speedup vs baseline: 1.1702x; 1.1702x over previous
//
#include <hip/hip_runtime.h>
#include <hip/hip_bf16.h>
#include <stdint.h>

#define BATCH 4
#define SEQ   4096
#define DIM   2048
#define NFREQ 1025
#define NCPLX 1024
#define ROWS  (BATCH*SEQ)   // 16384

// fused chunk decomposition
#define SCH  16            // rows per block (sequential, cumsum in regs)
#define NSC  (SEQ/SCH)     // 256 chunks per batch
#define NSCG 16            // chunks per scan group
#define NGRP (NSC/NSCG)    // 16 groups

#define SPEC_STRIDE 257    // uint4 per row: 256 pair-packed + 1 extra (k=512)

typedef __bf16 bf16x8 __attribute__((ext_vector_type(8)));
typedef float  f32x4  __attribute__((ext_vector_type(4)));

__device__ __forceinline__ int drev4(int n) {  // reverse 5 base-4 digits of 10-bit n
  return ((n&3)<<8) | (((n>>2)&3)<<6) | (((n>>4)&3)<<4) | (((n>>6)&3)<<2) | ((n>>8)&3);
}
#define ZI(i) ((i) + ((i)>>4))   // LDS pad: every 16 elems -> +1

__device__ __forceinline__ float2 cmulf(float2 a, float2 b) {
  return make_float2(a.x*b.x - a.y*b.y, a.x*b.y + a.y*b.x);
}
// complex multiply BOTH packed rows (xy, zw) by twiddle w
__device__ __forceinline__ float4 cmul2(float4 v, float2 w) {
  return make_float4(v.x*w.x - v.y*w.y, v.x*w.y + v.y*w.x,
                     v.z*w.x - v.w*w.y, v.z*w.y + v.w*w.x);
}
__device__ __forceinline__ float4 f4add(float4 a, float4 b){
  return make_float4(a.x+b.x, a.y+b.y, a.z+b.z, a.w+b.w);
}
__device__ __forceinline__ float4 f4sub(float4 a, float4 b){
  return make_float4(a.x-b.x, a.y-b.y, a.z-b.z, a.w-b.w);
}

__device__ __forceinline__ unsigned short f2bf(float f) {
  union { float f; unsigned u; } v; v.f = f;
  unsigned r = v.u + 0x7fffu + ((v.u >> 16) & 1u);
  return (unsigned short)(r >> 16);
}
__device__ __forceinline__ unsigned packbf(float2 v) {
  return (unsigned)f2bf(v.x) | ((unsigned)f2bf(v.y) << 16);
}
__device__ __forceinline__ float2 unpackbf(unsigned u) {
  union { unsigned u; float f; } a, b;
  a.u = u << 16; b.u = u & 0xffff0000u;
  return make_float2(a.f, b.f);
}

// ---------------- dual-row radix-4 butterflies on interleaved float4 ----------
template<int INV>
__device__ __forceinline__ void bfly4d(float4* zz, int i0, int q,
                                       float2 w1, float2 w2, float2 w3) {
  float4 x0 = zz[ZI(i0)];
  float4 x1 = cmul2(zz[ZI(i0+q)],   w1);
  float4 x2 = cmul2(zz[ZI(i0+2*q)], w2);
  float4 x3 = cmul2(zz[ZI(i0+3*q)], w3);
  float4 a = f4add(x0, x2), b = f4sub(x0, x2);
  float4 c = f4add(x1, x3), d = f4sub(x1, x3);
  zz[ZI(i0)]     = f4add(a, c);
  zz[ZI(i0+2*q)] = f4sub(a, c);
  if (!INV) {
    zz[ZI(i0+q)]   = make_float4(b.x+d.y, b.y-d.x, b.z+d.w, b.w-d.z);
    zz[ZI(i0+3*q)] = make_float4(b.x-d.y, b.y+d.x, b.z-d.w, b.w+d.z);
  } else {
    zz[ZI(i0+q)]   = make_float4(b.x-d.y, b.y+d.x, b.z-d.w, b.w+d.z);
    zz[ZI(i0+3*q)] = make_float4(b.x+d.y, b.y-d.x, b.z+d.w, b.w-d.z);
  }
}
template<int INV>
__device__ __forceinline__ void bfly4d_nw(float4* zz, int i0) {  // q=1, no twiddle
  float4 x0=zz[ZI(i0)], x1=zz[ZI(i0+1)], x2=zz[ZI(i0+2)], x3=zz[ZI(i0+3)];
  float4 a = f4add(x0, x2), b = f4sub(x0, x2);
  float4 c = f4add(x1, x3), d = f4sub(x1, x3);
  zz[ZI(i0)]   = f4add(a, c);
  zz[ZI(i0+2)] = f4sub(a, c);
  if (!INV) {
    zz[ZI(i0+1)] = make_float4(b.x+d.y, b.y-d.x, b.z+d.w, b.w-d.z);
    zz[ZI(i0+3)] = make_float4(b.x-d.y, b.y+d.x, b.z-d.w, b.w+d.z);
  } else {
    zz[ZI(i0+1)] = make_float4(b.x-d.y, b.y+d.x, b.z-d.w, b.w+d.z);
    zz[ZI(i0+3)] = make_float4(b.x+d.y, b.y-d.x, b.z+d.w, b.w-d.z);
  }
}

// dual-row 1024-pt radix-4 DIT on interleaved array: barriers serve TWO rows
template<int INV>
__device__ __forceinline__ void fftd(float4* zz, int tid, const float2* tw1) {
  bfly4d_nw<INV>(zz, tid*4);
  __syncthreads();
#pragma unroll
  for (int s = 0; s < 4; ++s) {
    const int lq = 2 + 2*s;          // q = 4,16,64,256
    const int q  = 1 << lq;
    int j = tid & (q-1), g = tid >> lq;
    int base = (g << (lq+2)) + j;
    float2 w1 = tw1[s]; if (INV) w1.y = -w1.y;
    float2 w2 = cmulf(w1, w1), w3 = cmulf(w2, w1);
    bfly4d<INV>(zz, base, q, w1, w2, w3);
    __syncthreads();
  }
}

__device__ __forceinline__ void make_tw1(int tid, float2* tw1) {
#pragma unroll
  for (int s = 0; s < 4; ++s) {
    const int lq = 2 + 2*s;
    const int q  = 1 << lq;
    int j = tid & (q-1);
    float ang = -6.2831853071795864769f * (float)j / (float)(4*q);
    float sw, cw; __sincosf(ang, &sw, &cw);
    tw1[s] = make_float2(cw, sw);
  }
}

// unpack packed-real spectrum for BOTH interleaved rows (k=tid and k=tid+256)
__device__ __forceinline__ void unpack_row2(const float4* zz, int tid,
    float cwA, float swA, float cwB, float swB,
    float2& vA, float2& vAp, float2& vB, float2& vBp,
    float2& uA, float2& uAp, float2& uB, float2& uBp) {
  float4 ZkA = zz[ZI(tid)],     ZnA = zz[ZI((NCPLX - tid) & (NCPLX-1))];
  float4 ZkB = zz[ZI(tid+256)], ZnB = zz[ZI(768 - tid)];
  { // row0 (.x,.y)
    float Er = 0.5f*(ZkA.x + ZnA.x), Ei = 0.5f*(ZkA.y - ZnA.y);
    float dr = 0.5f*(ZkA.x - ZnA.x), di = 0.5f*(ZkA.y + ZnA.y);
    vA  = make_float2( Er + cwA*di + swA*dr,  Ei + swA*di - cwA*dr);
    vAp = make_float2( Er - cwA*di - swA*dr, -Ei + swA*di - cwA*dr);
    float Fr = 0.5f*(ZkB.x + ZnB.x), Fi = 0.5f*(ZkB.y - ZnB.y);
    float er = 0.5f*(ZkB.x - ZnB.x), ei = 0.5f*(ZkB.y + ZnB.y);
    vB  = make_float2( Fr + cwB*ei + swB*er,  Fi + swB*ei - cwB*er);
    vBp = make_float2( Fr - cwB*ei - swB*er, -Fi + swB*ei - cwB*er);
  }
  { // row1 (.z,.w)
    float Er = 0.5f*(ZkA.z + ZnA.z), Ei = 0.5f*(ZkA.w - ZnA.w);
    float dr = 0.5f*(ZkA.z - ZnA.z), di = 0.5f*(ZkA.w + ZnA.w);
    uA  = make_float2( Er + cwA*di + swA*dr,  Ei + swA*di - cwA*dr);
    uAp = make_float2( Er - cwA*di - swA*dr, -Ei + swA*di - cwA*dr);
    float Fr = 0.5f*(ZkB.z + ZnB.z), Fi = 0.5f*(ZkB.w - ZnB.w);
    float er = 0.5f*(ZkB.z - ZnB.z), ei = 0.5f*(ZkB.w + ZnB.w);
    uB  = make_float2( Fr + cwB*ei + swB*er,  Fi + swB*ei - cwB*er);
    uBp = make_float2( Fr - cwB*ei - swB*er, -Fi + swB*ei - cwB*er);
  }
}

// ============ merged fwd_fused + wfft, 2 interleaved rows per FFT pass ========
__global__ __launch_bounds__(256) void fwd_wfft(const float* __restrict__ x,
                                                const float* __restrict__ w,
                                                const float* __restrict__ kvs,
                                                uint4* __restrict__ spec,
                                                float2* __restrict__ partial,
                                                unsigned short* __restrict__ H) {
  __shared__ __align__(16) float4 zz[ZI(1023)+2];   // 17.4KB; wfft reuses as hrow
  const int tid = threadIdx.x;

  float2 tw1[4];
  make_tw1(tid, tw1);
  const int kA = tid, kB = tid + 256;
  float swA, cwA, swB, cwB;   // e^{-i pi k/1024}
  __sincosf(-3.14159265358979323846f * (float)kA / 1024.0f, &swA, &cwA);
  __sincosf(-3.14159265358979323846f * (float)kB / 1024.0f, &swB, &cwB);
  int id0 = ZI(drev4(2*tid)),     id1 = ZI(drev4(2*tid+1));
  int id2 = ZI(drev4(2*tid+512)), id3 = ZI(drev4(2*tid+513));

  if (blockIdx.x >= BATCH*NSC) {
    // ---- wfft path: 2 W rows per block, interleaved ----
    const int e0 = (blockIdx.x - BATCH*NSC) * 2;
    const float* wr0 = w + (size_t)e0 * DIM;
    const float* wr1 = wr0 + DIM;
    float4 a0 = ((const float4*)wr0)[tid], a1 = ((const float4*)wr0)[tid + 256];
    float4 b0 = ((const float4*)wr1)[tid], b1 = ((const float4*)wr1)[tid + 256];
    zz[id0] = make_float4(a0.x, a0.y, b0.x, b0.y);
    zz[id1] = make_float4(a0.z, a0.w, b0.z, b0.w);
    zz[id2] = make_float4(a1.x, a1.y, b1.x, b1.y);
    zz[id3] = make_float4(a1.z, a1.w, b1.z, b1.w);
    __syncthreads();
    fftd<0>(zz, tid, tw1);
    float2 vA, vAp, vB, vBp, uA, uAp, uB, uBp;
    unpack_row2(zz, tid, cwA, swA, cwB, swB, vA, vAp, vB, vBp, uA, uAp, uB, uBp);
    float4 Z5 = make_float4(0,0,0,0);
    if (tid == 0) Z5 = zz[ZI(512)];
    __syncthreads();                      // zz reads done; reuse as hrow
    unsigned short* hr0 = (unsigned short*)zz;
    unsigned short* hr1 = hr0 + 2048;
    const float invN = 1.0f/2048.0f, twoN = 2.0f/2048.0f;
    float aA = (tid == 0) ? invN : twoN;
    hr0[tid]        = f2bf(aA   * vA.x);   hr1[tid]        = f2bf(aA   * uA.x);
    hr0[1024 - tid] = f2bf(aA   * vAp.x);  hr1[1024 - tid] = f2bf(aA   * uAp.x);
    hr0[256 + tid]  = f2bf(twoN * vB.x);   hr1[256 + tid]  = f2bf(twoN * uB.x);
    hr0[768 - tid]  = f2bf(twoN * vBp.x);  hr1[768 - tid]  = f2bf(twoN * uBp.x);
    if (tid) {
      hr0[1024 + tid] = f2bf(twoN * vA.y);  hr1[1024 + tid] = f2bf(twoN * uA.y);
      hr0[2048 - tid] = f2bf(twoN * vAp.y); hr1[2048 - tid] = f2bf(twoN * uAp.y);
    }
    hr0[1280 + tid] = f2bf(twoN * vB.y);   hr1[1280 + tid] = f2bf(twoN * uB.y);
    hr0[1792 - tid] = f2bf(twoN * vBp.y);  hr1[1792 - tid] = f2bf(twoN * uBp.y);
    if (tid == 0) {
      hr0[512]  = f2bf(twoN * Z5.x);  hr0[1536] = f2bf(twoN * (-Z5.y));
      hr1[512]  = f2bf(twoN * Z5.z);  hr1[1536] = f2bf(twoN * (-Z5.w));
    }
    __syncthreads();
    ((uint4*)(H + (size_t)e0 * DIM))[tid]       = ((const uint4*)hr0)[tid];
    ((uint4*)(H + (size_t)(e0 + 1) * DIM))[tid] = ((const uint4*)hr1)[tid];
    return;
  }

  // ---- fwd path: 16 rows, 2 per FFT pass, prefetched ----
  const int sc = blockIdx.x & (NSC-1), b = blockIdx.x >> 8;
  float2 sA={0,0}, sAp={0,0}, sB={0,0}, sBp={0,0}, s5={0,0};
  const size_t row0 = (size_t)b*SEQ + (size_t)sc*SCH;
  const float* xrow = x + row0*DIM;
  const float kvA = kvs[kA], kvAp = kvs[NCPLX - kA], kvB = kvs[kB], kvBp = kvs[768 - tid];

  float4 c0 = ((const float4*)xrow)[tid],         c1 = ((const float4*)xrow)[tid + 256];
  float4 d0 = ((const float4*)(xrow+DIM))[tid],   d1 = ((const float4*)(xrow+DIM))[tid + 256];

  for (int s = 0; s < SCH; s += 2) {
    float4 n0, n1, n2, n3;
    if (s+2 < SCH) {
      const float* nx0 = xrow + (size_t)(s+2)*DIM;
      const float* nx1 = nx0 + DIM;
      n0 = ((const float4*)nx0)[tid]; n1 = ((const float4*)nx0)[tid + 256];
      n2 = ((const float4*)nx1)[tid]; n3 = ((const float4*)nx1)[tid + 256];
    }
    zz[id0] = make_float4(c0.x, c0.y, d0.x, d0.y);
    zz[id1] = make_float4(c0.z, c0.w, d0.z, d0.w);
    zz[id2] = make_float4(c1.x, c1.y, d1.x, d1.y);
    zz[id3] = make_float4(c1.z, c1.w, d1.z, d1.w);
    __syncthreads();
    fftd<0>(zz, tid, tw1);
    float2 vA, vAp, vB, vBp, uA, uAp, uB, uBp;
    unpack_row2(zz, tid, cwA, swA, cwB, swB, vA, vAp, vB, vBp, uA, uAp, uB, uBp);
    // accumulate row s then row s+1 (same order as sequential version)
    sA.x += vA.x;  sA.y += vA.y;   sAp.x += vAp.x; sAp.y += vAp.y;
    sB.x += vB.x;  sB.y += vB.y;   sBp.x += vBp.x; sBp.y += vBp.y;
    sA.x += uA.x;  sA.y += uA.y;   sAp.x += uAp.x; sAp.y += uAp.y;
    sB.x += uB.x;  sB.y += uB.y;   sBp.x += uBp.x; sBp.y += uBp.y;
    uint4* sp0 = spec + (row0 + s) * SPEC_STRIDE;
    uint4* sp1 = sp0 + SPEC_STRIDE;
    sp0[tid] = make_uint4(packbf(vA), packbf(vAp), packbf(vB), packbf(vBp));
    sp1[tid] = make_uint4(packbf(uA), packbf(uAp), packbf(uB), packbf(uBp));
    if (tid == 0) {
      float4 Z5 = zz[ZI(512)];
      float2 v5 = make_float2(Z5.x, -Z5.y);
      float2 u5 = make_float2(Z5.z, -Z5.w);
      s5.x += v5.x + u5.x; s5.y += v5.y + u5.y;
      ((unsigned*)(sp0 + 256))[0] = packbf(v5);
      ((unsigned*)(sp1 + 256))[0] = packbf(u5);
    }
    __syncthreads();                                   // zz free for next scatter
    c0 = n0; c1 = n1; d0 = n2; d1 = n3;
  }
  float2* pp = partial + ((size_t)(b*NSC + sc)) * NFREQ;
  pp[kA]          = make_float2(kvA*sA.x,  kvA*sA.y);
  pp[NCPLX - kA]  = make_float2(kvAp*sAp.x, kvAp*sAp.y);
  pp[kB]          = make_float2(kvB*sB.x,  kvB*sB.y);
  pp[768 - tid]   = make_float2(kvBp*sBp.x, kvBp*sBp.y);
  if (tid == 0) { float kv5 = kvs[512]; pp[512] = make_float2(kv5*s5.x, kv5*s5.y); }
}

// ============ scanA: exclusive scan within group; write RAW group totals ======
__global__ __launch_bounds__(256) void scanA(float2* __restrict__ partial,
                                             float2* __restrict__ gtot) {
  int kc = blockIdx.x % 5, g = (blockIdx.x / 5) % NGRP, b = blockIdx.x / (5*NGRP);
  int k = kc*256 + threadIdx.x;
  if (k >= NFREQ) return;
  float2* p = partial + ((size_t)(b*NSC + g*NSCG)) * NFREQ + k;
  float2 run = {0.f, 0.f};
#pragma unroll
  for (int i = 0; i < NSCG; ++i) {
    float2 t = p[(size_t)i*NFREQ];
    p[(size_t)i*NFREQ] = run;                          // exclusive within group
    run.x += t.x; run.y += t.y;
  }
  gtot[((size_t)(b*NGRP + g)) * NFREQ + k] = run;      // raw group total
}

// ============ inv_fused: inline group-prefix + cumsum-apply -> spectral G =====
__global__ __launch_bounds__(256) void inv_fused(const uint4* __restrict__ spec,
                                                 const float* __restrict__ kvs,
                                                 const float* __restrict__ qs_,
                                                 const float2* __restrict__ partial,
                                                 const float2* __restrict__ gtot,
                                                 unsigned short* __restrict__ G) {
  __shared__ __align__(16) unsigned short grow[2][2048];   // double-buffered
  const int tid = threadIdx.x;
  const int sc = blockIdx.x & (NSC-1), b = blockIdx.x >> 8;
  const int kA = tid, kB = tid + 256;

  float ksA = kvs[kA], ksAp = kvs[NCPLX - kA], ksB = kvs[kB], ksBp = kvs[768 - tid];
  float qsA = qs_[kA], qsAp = qs_[NCPLX - kA], qsB = qs_[kB], qsBp = qs_[768 - tid];

  const float2* pp = partial + ((size_t)(b*NSC + sc)) * NFREQ;
  float2 CA  = pp[kA], CAp = pp[NCPLX-kA], CB = pp[kB], CBp = pp[768-tid];
  float ks5 = kvs[512], qs5 = qs_[512];
  float2 C5 = pp[512];
  // inline exclusive prefix over RAW group totals (replaces scanB kernel)
  {
    const int g = sc >> 4;
    const float2* gb = gtot + (size_t)b*NGRP*NFREQ;
    for (int gg = 0; gg < g; ++gg) {
      const float2* gr = gb + (size_t)gg*NFREQ;
      float2 a0 = gr[kA], a1 = gr[NCPLX-kA], a2 = gr[kB], a3 = gr[768-tid];
      CA.x += a0.x; CA.y += a0.y;   CAp.x += a1.x; CAp.y += a1.y;
      CB.x += a2.x; CB.y += a2.y;   CBp.x += a3.x; CBp.y += a3.y;
      if (tid == 0) { float2 a5 = gr[512]; C5.x += a5.x; C5.y += a5.y; }
    }
  }

  const size_t row0 = (size_t)b*SEQ + (size_t)sc*SCH;
  const uint4* sprow = spec + row0 * SPEC_STRIDE;
  uint4 sp = sprow[tid];
  unsigned spN = ((const unsigned*)(sprow + 256))[0];

  for (int s = 0; s < SCH; ++s) {
    uint4 spn; unsigned spNn;
    if (s+1 < SCH) {
      const uint4* nr = sprow + (size_t)(s+1) * SPEC_STRIDE;
      spn = nr[tid]; spNn = ((const unsigned*)(nr + 256))[0];
    }
    unsigned short* gw = grow[s & 1];
    float2 vA = unpackbf(sp.x), vAp = unpackbf(sp.y);
    float2 vB = unpackbf(sp.z), vBp = unpackbf(sp.w);
    CA.x  += vA.x*ksA;   CA.y  += vA.y*ksA;
    CAp.x += vAp.x*ksAp; CAp.y += vAp.y*ksAp;
    CB.x  += vB.x*ksB;   CB.y  += vB.y*ksB;
    CBp.x += vBp.x*ksBp; CBp.y += vBp.y*ksBp;
    float2 qvA  = make_float2(qsA *(vA.x*CA.x  - vA.y*CA.y),  qsA *(vA.x*CA.y  + vA.y*CA.x));
    float2 qvAp = make_float2(qsAp*(vAp.x*CAp.x- vAp.y*CAp.y),qsAp*(vAp.x*CAp.y+ vAp.y*CAp.x));
    float2 qvB  = make_float2(qsB *(vB.x*CB.x  - vB.y*CB.y),  qsB *(vB.x*CB.y  + vB.y*CB.x));
    float2 qvBp = make_float2(qsBp*(vBp.x*CBp.x- vBp.y*CBp.y),qsBp*(vBp.x*CBp.y+ vBp.y*CBp.x));
    // scatter spectral row: real cols {t,1024-t,256+t,768-t}, imag cols 1024+k
    gw[tid]        = f2bf(qvA.x);
    gw[1024 - tid] = f2bf(qvAp.x);
    gw[256 + tid]  = f2bf(qvB.x);
    gw[768 - tid]  = f2bf(qvBp.x);
    if (tid) {
      gw[1024 + tid] = f2bf(qvA.y);
      gw[2048 - tid] = f2bf(qvAp.y);
    }
    gw[1280 + tid] = f2bf(qvB.y);
    gw[1792 - tid] = f2bf(qvBp.y);
    if (tid == 0) {
      float2 v5 = unpackbf(spN);
      C5.x += v5.x*ks5; C5.y += v5.y*ks5;
      gw[512]  = f2bf(qs5*(v5.x*C5.x - v5.y*C5.y));
      gw[1536] = f2bf(qs5*(v5.x*C5.y + v5.y*C5.x));
    }
    __syncthreads();
    ((uint4*)(G + (row0 + s) * DIM))[tid] = ((const uint4*)gw)[tid];
    // no trailing barrier: next iteration scatters into the other buffer
    sp = spn; spN = spNn;
  }
}

// ============ 256x256 8-phase GEMM: C[M,N] = A[M,K] * B[N,K]^T, bf16->fp32 =====
#define NKT (DIM/64)      // 32 K-tiles
#define NIT (NKT/2)       // 16 iterations of 2 K-tiles

#define BAR()  __builtin_amdgcn_s_barrier()
#define VMW(N) do{ asm volatile("s_waitcnt vmcnt(" #N ")" ::: "memory"); __builtin_amdgcn_sched_barrier(0); }while(0)

#define LOADA(B_, MH) do{ _Pragma("unroll") for (int m_=0;m_<4;++m_) _Pragma("unroll") for (int kk_=0;kk_<2;++kk_){ \
    int rA_ = wm*64 + m_*16 + l15; \
    aF[m_][kk_] = *(const bf16x8*)(smem + ((B_)*2+(MH))*16384 + rA_*128 + ((kk_*64 + lhi*16) ^ ((rA_&7)<<4))); } }while(0)

#define LOADB(DST, B_, NH) do{ _Pragma("unroll") for (int n_=0;n_<2;++n_) _Pragma("unroll") for (int kk_=0;kk_<2;++kk_){ \
    int rB_ = wn*32 + n_*16 + l15; \
    DST[n_][kk_] = *(const bf16x8*)(smem + 65536 + ((B_)*2+(NH))*16384 + rB_*128 + ((kk_*64 + lhi*16) ^ ((rB_&7)<<4))); } }while(0)

#define MM(MH, NH, BF) do{ __builtin_amdgcn_s_setprio(1); \
    _Pragma("unroll") for (int kk_=0;kk_<2;++kk_) _Pragma("unroll") for (int m_=0;m_<4;++m_) _Pragma("unroll") for (int n_=0;n_<2;++n_) \
      acc[MH][NH][m_][n_] = __builtin_amdgcn_mfma_f32_16x16x32_bf16(aF[m_][kk_], BF[n_][kk_], acc[MH][NH][m_][n_], 0, 0, 0); \
    __builtin_amdgcn_s_setprio(0); }while(0)

#define STAGEH(REG, B_, H_, GP, ROW0, KT) do{ _Pragma("unroll") for (int c_=0;c_<2;++c_){ \
    int ci_ = c_*512 + tid; int r_ = ci_>>3, sl_ = ci_&7; \
    const unsigned short* sp_ = (GP) + (size_t)((ROW0) + (H_)*128 + r_)*DIM + (KT) + ((sl_ ^ (r_&7))*8); \
    __builtin_amdgcn_global_load_lds((const __attribute__((address_space(1))) void*)sp_, \
      (__attribute__((address_space(3))) void*)(smem + (REG) + ((B_)*2+(H_))*16384 + ci_*16), 16, 0, 0); } }while(0)

__global__ __launch_bounds__(512, 2) void gemm256(const unsigned short* __restrict__ A,
                                                  const unsigned short* __restrict__ B,
                                                  float* __restrict__ C) {
  __shared__ __align__(16) char smem[131072];
  const int tid = threadIdx.x;
  const int lane = tid & 63;
  const int wid  = tid >> 6;
  const int wm = wid >> 2, wn = wid & 3;
  const int l15 = lane & 15, lhi = lane >> 4;

  // XCD-grouped swizzle: XCD j (= bid%8) owns bm in [8j, 8j+8) for all bn
  const int xj = blockIdx.x & 7, tt = blockIdx.x >> 3;
  const int bm = xj * 8 + (tt >> 3), bn = tt & 7;
  const int m0 = bm * 256, n0 = bn * 256;

  f32x4 acc[2][2][4][2] = {};
  bf16x8 aF[4][2], bF0[2][2], bF1[2][2];

  STAGEH(0,     0,0, A, m0, 0);  STAGEH(65536, 0,0, B, n0, 0);
  STAGEH(65536, 0,1, B, n0, 0);  STAGEH(0,     0,1, A, m0, 0);
  STAGEH(0,     1,0, A, m0, 64); STAGEH(65536, 1,0, B, n0, 64);
  STAGEH(65536, 1,1, B, n0, 64); STAGEH(0,     1,1, A, m0, 64);
  VMW(8);
  BAR();

#pragma unroll 1
  for (int j = 0; j < NIT-1; ++j) {
    const int kA = (2*j+2)*64, kB = (2*j+3)*64;
    LOADA(0,0); LOADB(bF0, 0,0);
    BAR(); MM(0,0,bF0); BAR();
    LOADB(bF1, 0,1);
    STAGEH(0, 0,0, A, m0, kA); STAGEH(65536, 0,0, B, n0, kA);
    BAR(); MM(0,1,bF1); BAR();
    LOADA(0,1);
    STAGEH(65536, 0,1, B, n0, kA);
    BAR(); MM(1,0,bF0); BAR();
    STAGEH(0, 0,1, A, m0, kA);
    VMW(8);
    BAR(); MM(1,1,bF1); BAR();
    LOADA(1,0); LOADB(bF0, 1,0);
    BAR(); MM(0,0,bF0); BAR();
    LOADB(bF1, 1,1);
    STAGEH(0, 1,0, A, m0, kB); STAGEH(65536, 1,0, B, n0, kB);
    BAR(); MM(0,1,bF1); BAR();
    LOADA(1,1);
    STAGEH(65536, 1,1, B, n0, kB);
    BAR(); MM(1,0,bF0); BAR();
    STAGEH(0, 1,1, A, m0, kB);
    VMW(8);
    BAR(); MM(1,1,bF1); BAR();
  }
  LOADA(0,0); LOADB(bF0, 0,0);
  BAR(); MM(0,0,bF0); BAR();
  LOADB(bF1, 0,1);
  BAR(); MM(0,1,bF1); BAR();
  LOADA(0,1);
  BAR(); MM(1,0,bF0); BAR();
  VMW(0);
  BAR(); MM(1,1,bF1); BAR();
  LOADA(1,0); LOADB(bF0, 1,0);
  BAR(); MM(0,0,bF0); BAR();
  LOADB(bF1, 1,1);
  BAR(); MM(0,1,bF1); BAR();
  LOADA(1,1);
  BAR(); MM(1,0,bF0); BAR();
  BAR(); MM(1,1,bF1); BAR();

  const int crow = lhi * 4;
#pragma unroll
  for (int mh = 0; mh < 2; ++mh)
#pragma unroll
    for (int nh = 0; nh < 2; ++nh)
#pragma unroll
      for (int m_ = 0; m_ < 4; ++m_)
#pragma unroll
        for (int n_ = 0; n_ < 2; ++n_) {
          float* cp = C + (size_t)(m0 + mh*128 + wm*64 + m_*16 + crow) * DIM
                        + (n0 + nh*128 + wn*32 + n_*16 + l15);
#pragma unroll
          for (int j2 = 0; j2 < 4; ++j2)
            cp[(size_t)j2 * DIM] = acc[mh][nh][m_][n_][j2];
        }
}

// ---------------- launch -------------------------------------------------------
extern "C" void kernel_launch(void* const* d_in, const int* in_sizes, int n_in,
                              void* d_out, int out_size, void* d_ws, size_t ws_size,
                              hipStream_t stream) {
  const float* x    = (const float*)d_in[0];
  const float* qry  = (const float*)d_in[1];
  const float* kvs  = (const float*)d_in[2];
  const float* wout = (const float*)d_in[3];
  float* out = (float*)d_out;

  char* ws = (char*)d_ws;
  size_t off = 0;
  uint4* spec = (uint4*)(ws + off);                     // 67.4 MB
  off += (size_t)ROWS * SPEC_STRIDE * sizeof(uint4);
  off = (off + 255) & ~(size_t)255;
  unsigned short* G = (unsigned short*)(ws + off);      // 67 MB (spectral A)
  off += (size_t)ROWS * DIM * sizeof(unsigned short);
  off = (off + 255) & ~(size_t)255;
  unsigned short* H = (unsigned short*)(ws + off);      // 8.4 MB (spectral W)
  off += (size_t)DIM * DIM * sizeof(unsigned short);
  off = (off + 255) & ~(size_t)255;
  float2* partial = (float2*)(ws + off);                // 8.4 MB
  off += (size_t)BATCH * NSC * NFREQ * sizeof(float2);
  off = (off + 255) & ~(size_t)255;
  float2* gtot = (float2*)(ws + off);                   // 0.5 MB (raw group totals)
  off += (size_t)BATCH * NGRP * NFREQ * sizeof(float2);

  hipLaunchKernelGGL(fwd_wfft,  dim3(BATCH*NSC + DIM/2), dim3(256), 0, stream, x, wout, kvs, spec, partial, H);
  hipLaunchKernelGGL(scanA,     dim3(BATCH*NGRP*5),      dim3(256), 0, stream, partial, gtot);
  hipLaunchKernelGGL(inv_fused, dim3(BATCH*NSC),         dim3(256), 0, stream, spec, kvs, qry, partial, gtot, G);
  hipLaunchKernelGGL(gemm256,   dim3((ROWS/256)*(DIM/256)), dim3(512), 0, stream, G, H, out);
}